// Round 8
// baseline (223.013 us; speedup 1.0000x reference)
//
#include <hip/hip_runtime.h>
#include <stdint.h>

#define NROWS 16384
#define NCODES 8192
#define DIM 256

#define BROWS 64
#define PCOLS 2048
#define BCOLS 64            // 64-code column tiles (8 KB buffers)
#define NCITER (PCOLS / BCOLS)   // 32 citers x 4 K-chunks = 128 chunks

// workspace layout (bytes)
#define OFF_C2D   0u          // double[8192]             65536
#define OFF_PTOP  65536u      // u64[16384][4][2]       1048576
#define OFF_LSLOT 1114112u    // double[256]               2048
#define OFF_Z16   1116288u    // u16[16384*256]         8388608
#define OFF_CB16  9504896u    // u16[8192*256]          4194304

typedef __attribute__((ext_vector_type(8))) short bf16x8;
typedef __attribute__((ext_vector_type(4))) float f32x4;

__device__ __forceinline__ uint32_t enc_f32(float f) {
  uint32_t u = __float_as_uint(f);
  return (u & 0x80000000u) ? ~u : (u | 0x80000000u);
}
__device__ __forceinline__ unsigned short f2bf(float f) {
  uint32_t u = __float_as_uint(f);
  u += 0x7fffu + ((u >> 16) & 1u);   // RNE (inputs finite)
  return (unsigned short)(u >> 16);
}
__device__ __forceinline__ void gload16(const void* g, void* l) {
  __builtin_amdgcn_global_load_lds(
      (const __attribute__((address_space(1))) unsigned int*)g,
      (__attribute__((address_space(3))) unsigned int*)l, 16, 0, 0);
}
__device__ __forceinline__ unsigned long long umin64(unsigned long long a,
                                                     unsigned long long b) {
  return a < b ? a : b;
}

// ---- kernel 1: prep — z cvt | cb cvt + fp64 norms | loss-slot init ----
__global__ __launch_bounds__(256) void k_prep(
    const float* __restrict__ z, const float* __restrict__ cb,
    unsigned short* __restrict__ z16, unsigned short* __restrict__ cb16,
    double* __restrict__ c2d, double* __restrict__ lossSlots) {
  const int bid = blockIdx.x;
  if (bid < 4096) {
    const int i = bid * 256 + threadIdx.x;
    float4 v = reinterpret_cast<const float4*>(z)[i];
    ushort4 o = {f2bf(v.x), f2bf(v.y), f2bf(v.z), f2bf(v.w)};
    reinterpret_cast<ushort4*>(z16)[i] = o;
  } else if (bid < 6144) {
    const int w = threadIdx.x >> 6, lane = threadIdx.x & 63;
    const int j = (bid - 4096) * 4 + w;
    float4 v = *reinterpret_cast<const float4*>(cb + (size_t)j * DIM + lane * 4);
    ushort4 o = {f2bf(v.x), f2bf(v.y), f2bf(v.z), f2bf(v.w)};
    *reinterpret_cast<ushort4*>(cb16 + (size_t)j * DIM + lane * 4) = o;
    double s = (double)v.x * v.x + (double)v.y * v.y +
               (double)v.z * v.z + (double)v.w * v.w;
#pragma unroll
    for (int off = 32; off > 0; off >>= 1) s += __shfl_xor(s, off);
    if (lane == 0) c2d[j] = s;
  } else {
    lossSlots[threadIdx.x] = 0.0;
  }
}

// ---- kernel 2: panel-persistent MFMA dot-max ----
// 1024 blocks: 4 col-panels x 256 row-panels, XCD-swizzled. Per block:
// 64 rows x 2048 cols, 32 citers of 64 cols x 4 K-chunks (K=64 each).
// Round-8 structure: 8 KB B-buffers x3 (26.6 KB LDS total) -> 4 blocks/CU
// resident (zero tail, 16 waves/CU); ONE barrier per chunk:
//   {vmcnt(2); s_barrier; STAGE(c+2); COMPUTE(c)}
// publication: per-wave vmcnt + barrier join => chunk c staged by ALL waves;
// STAGE(c+2) post-barrier overwrites buf((c-1)%3), finished by all waves
// (depth 2 < nbuf 3). Counted vmcnt (never 0 until last chunk).
// launch_bounds (256,2): round-4 lesson — never cap regs below working set.
__global__ __launch_bounds__(256, 2) void k_score(
    const unsigned short* __restrict__ z16, const unsigned short* __restrict__ cb16,
    unsigned long long* __restrict__ ptop) {
  __shared__ unsigned short pool[3 * BCOLS * 64];   // 3 x 8 KB
  __shared__ unsigned long long top_sh[BROWS][2][2];

  const int tid = threadIdx.x;
  const int lane = tid & 63;
  const int w = tid >> 6;
  const int wr = w >> 1, wc = w & 1;
  const int l15 = lane & 15, l4 = lane >> 4;

  // bijective XCD swizzle (1024 % 8 == 0), col-panel-major
  const int wg = (blockIdx.x & 7) * 128 + (blockIdx.x >> 3);
  const int panel = wg >> 8;          // 0..3
  const int row0 = (wg & 255) * BROWS;
  const int col0 = panel * PCOLS;

  // ---- A direct global -> registers (rows wr*32.., whole K) ----
  bf16x8 a_reg[2][8];
#pragma unroll
  for (int mi = 0; mi < 2; ++mi)
#pragma unroll
    for (int kt = 0; kt < 8; ++kt)
      a_reg[mi][kt] = *reinterpret_cast<const bf16x8*>(
          z16 + (size_t)(row0 + wr * 32 + mi * 16 + l15) * DIM + kt * 32 + l4 * 8);
  // Drain A-loads so in-loop vmcnt counts ONLY stage loads (2/chunk).
  asm volatile("s_waitcnt vmcnt(0)" ::: "memory");
  __builtin_amdgcn_sched_barrier(0);

  // B staging constants (pre-swizzled global source; LDS stays linear).
  const int bc_loc = tid >> 3;                                         // 0..31
  const int kswz_e = ((((tid & 7) * 16) ^ (((tid >> 3) & 7) << 4)) >> 1);
  const unsigned wbase = (unsigned)w * 1024u;

#define STAGE(ci_, kc_, buf_) do {                                             \
    const unsigned short* gsrc_ = cb16 +                                       \
        (size_t)(col0 + (ci_) * BCOLS + bc_loc) * DIM + (kc_) * 64 + kswz_e;   \
    char* ldst_ = (char*)pool + (buf_) * 8192 + wbase;                         \
    gload16(gsrc_,            ldst_);                                          \
    gload16(gsrc_ + 32 * DIM, ldst_ + 4096);                                   \
  } while (0)

#define COMPUTE(kc_, buf_) do {                                                \
    _Pragma("unroll")                                                          \
    for (int kk_ = 0; kk_ < 2; ++kk_) {                                        \
      bf16x8 bf_[2];                                                           \
      _Pragma("unroll")                                                        \
      for (int ni_ = 0; ni_ < 2; ++ni_) {                                      \
        const int cI_ = wc * 32 + ni_ * 16 + l15;                              \
        const int kb_ = (kk_ * 64 + l4 * 16) ^ ((l15 & 7) << 4);               \
        bf_[ni_] = *reinterpret_cast<const bf16x8*>(                           \
            (const char*)pool + (buf_) * 8192 + cI_ * 128 + kb_);              \
      }                                                                        \
      _Pragma("unroll")                                                        \
      for (int mi_ = 0; mi_ < 2; ++mi_)                                        \
        _Pragma("unroll")                                                      \
        for (int ni_ = 0; ni_ < 2; ++ni_)                                      \
          acc[mi_][ni_] = __builtin_amdgcn_mfma_f32_16x16x32_bf16(             \
              a_reg[mi_][(kc_) * 2 + kk_], bf_[ni_], acc[mi_][ni_], 0, 0, 0);  \
    }                                                                          \
  } while (0)

// one barrier per chunk; stage issued right after barrier (max in-flight time)
#define CHN(kc_, bufR_, sci_, skc_, bufS_)                                     \
  asm volatile("s_waitcnt vmcnt(2)" ::: "memory");                             \
  __builtin_amdgcn_sched_barrier(0);                                           \
  __builtin_amdgcn_s_barrier();                                                \
  __builtin_amdgcn_sched_barrier(0);                                           \
  STAGE(sci_, skc_, bufS_);                                                    \
  __builtin_amdgcn_s_setprio(1);                                               \
  COMPUTE(kc_, bufR_);                                                         \
  __builtin_amdgcn_s_setprio(0);

#define CHT2(kc_, bufR_)                                                       \
  asm volatile("s_waitcnt vmcnt(2)" ::: "memory");                             \
  __builtin_amdgcn_sched_barrier(0);                                           \
  __builtin_amdgcn_s_barrier();                                                \
  __builtin_amdgcn_sched_barrier(0);                                           \
  __builtin_amdgcn_s_setprio(1);                                               \
  COMPUTE(kc_, bufR_);                                                         \
  __builtin_amdgcn_s_setprio(0);

#define CHT0(kc_, bufR_)                                                       \
  asm volatile("s_waitcnt vmcnt(0)" ::: "memory");                             \
  __builtin_amdgcn_sched_barrier(0);                                           \
  __builtin_amdgcn_s_barrier();                                                \
  __builtin_amdgcn_sched_barrier(0);                                           \
  __builtin_amdgcn_s_setprio(1);                                               \
  COMPUTE(kc_, bufR_);                                                         \
  __builtin_amdgcn_s_setprio(0);

#define ZERO_ACC() do {                                                        \
    _Pragma("unroll")                                                          \
    for (int mi_ = 0; mi_ < 2; ++mi_)                                          \
      _Pragma("unroll")                                                        \
      for (int ni_ = 0; ni_ < 2; ++ni_)                                        \
        acc[mi_][ni_] = (f32x4){0.f, 0.f, 0.f, 0.f};                           \
  } while (0)

#define EPI(ci_) do {                                                          \
    const uint32_t cbase = (uint32_t)(col0 + (ci_) * BCOLS + wc * 32 + l15);   \
    _Pragma("unroll")                                                          \
    for (int mi_ = 0; mi_ < 2; ++mi_)                                          \
      _Pragma("unroll")                                                        \
      for (int q_ = 0; q_ < 4; ++q_) {                                         \
        const int s_ = mi_ * 4 + q_;                                           \
        const float d0 = acc[mi_][0][q_], d1 = acc[mi_][1][q_];                \
        const float mv = fmaxf(d0, d1);                                        \
        const uint32_t mc = d1 > d0 ? cbase + 16u : cbase;                     \
        const bool g0 = mv > b0v[s_];                                          \
        const bool g1 = mv > b1v[s_];                                          \
        b1v[s_] = g0 ? b0v[s_] : (g1 ? mv : b1v[s_]);                          \
        b1c[s_] = g0 ? b0c[s_] : (g1 ? mc : b1c[s_]);                          \
        b0v[s_] = g0 ? mv : b0v[s_];                                           \
        b0c[s_] = g0 ? mc : b0c[s_];                                           \
      }                                                                        \
  } while (0)

// chunk c = 4*ci + kc, buf = c%3 = (ci+kc)%3; stage chunk c+2.
#define CITER_P0(ci_) ZERO_ACC();                                              \
  CHN(0, 0, ci_, 2, 2) CHN(1, 1, ci_, 3, 0)                                    \
  CHN(2, 2, (ci_) + 1, 0, 1) CHN(3, 0, (ci_) + 1, 1, 2) EPI(ci_);
#define CITER_P1(ci_) ZERO_ACC();                                              \
  CHN(0, 1, ci_, 2, 0) CHN(1, 2, ci_, 3, 1)                                    \
  CHN(2, 0, (ci_) + 1, 0, 2) CHN(3, 1, (ci_) + 1, 1, 0) EPI(ci_);
#define CITER_P2(ci_) ZERO_ACC();                                              \
  CHN(0, 2, ci_, 2, 1) CHN(1, 0, ci_, 3, 2)                                    \
  CHN(2, 1, (ci_) + 1, 0, 0) CHN(3, 2, (ci_) + 1, 1, 1) EPI(ci_);

  f32x4 acc[2][2];
  float b0v[8], b1v[8];
  uint32_t b0c[8], b1c[8];
#pragma unroll
  for (int s = 0; s < 8; ++s) {
    b0v[s] = -1e30f; b1v[s] = -1e30f; b0c[s] = 0u; b1c[s] = 0u;
  }

  // prologue: stage chunks 0,1
  STAGE(0, 0, 0);
  STAGE(0, 1, 1);

  // main: 10 superblocks x 3 citers (ci 0..29), then citer 30 + tail citer 31
  int ci = 0;
  for (int sb = 0; sb < 10; ++sb) {
    CITER_P0(ci) ++ci;
    CITER_P1(ci) ++ci;
    CITER_P2(ci) ++ci;
  }
  CITER_P0(30)
  // tail citer 31 (pattern P1; chunks 126,127 have no stage)
  ZERO_ACC();
  CHN(0, 1, 31, 2, 0) CHN(1, 2, 31, 3, 1)
  CHT2(2, 0) CHT0(3, 1) EPI(31);

  // ---- block end: top-2 butterfly over l15 lanes, wc-merge, plain store ----
#pragma unroll
  for (int mi = 0; mi < 2; ++mi)
#pragma unroll
    for (int q = 0; q < 4; ++q) {
      const int s = mi * 4 + q;
      unsigned long long p0 =
          ((unsigned long long)enc_f32(-2.0f * b0v[s]) << 32) | b0c[s];
      unsigned long long p1 =
          ((unsigned long long)enc_f32(-2.0f * b1v[s]) << 32) | b1c[s];
#pragma unroll
      for (int off = 1; off < 16; off <<= 1) {
        const unsigned long long o0 = __shfl_xor(p0, off);
        const unsigned long long o1 = __shfl_xor(p1, off);
        const unsigned long long hi = p0 > o0 ? p0 : o0;
        p0 = umin64(p0, o0);
        p1 = umin64(hi, umin64(p1, o1));
      }
      if (l15 == 0) {
        const int rloc = wr * 32 + mi * 16 + l4 * 4 + q;
        top_sh[rloc][wc][0] = p0;
        top_sh[rloc][wc][1] = p1;
      }
    }
  __syncthreads();
  if (tid < BROWS) {
    const unsigned long long a0 = top_sh[tid][0][0], a1 = top_sh[tid][0][1];
    const unsigned long long c0 = top_sh[tid][1][0], c1 = top_sh[tid][1][1];
    const unsigned long long hi = a0 > c0 ? a0 : c0;
    ptop[(size_t)(row0 + tid) * 8 + panel * 2 + 0] = umin64(a0, c0);
    ptop[(size_t)(row0 + tid) * 8 + panel * 2 + 1] = umin64(hi, umin64(a1, c1));
  }
#undef STAGE
#undef COMPUTE
#undef CHN
#undef CHT2
#undef CHT0
#undef ZERO_ACC
#undef EPI
#undef CITER_P0
#undef CITER_P1
#undef CITER_P2
}

// ---- kernel 3: parallel fp64 refine (8 fixed candidates) + gather + loss ----
// wave per row; 8 lane-groups of 8 each score one candidate concurrently.
// NO cross-block signaling / fences (round-6 lesson).
__global__ __launch_bounds__(256) void k_refine_out(
    const float* __restrict__ z, const float* __restrict__ cb,
    const double* __restrict__ c2d, const unsigned long long* __restrict__ ptop,
    float* __restrict__ out, double* __restrict__ lossSlots) {
  const int w = threadIdx.x >> 6;
  const int lane = threadIdx.x & 63;
  const int r = blockIdx.x * 4 + w;
  const int g = lane >> 3;     // candidate slot 0..7 ([panel][2])
  const int u = lane & 7;

  const uint32_t jg =
      (uint32_t)(ptop[(size_t)r * 8 + g] & 0xFFFFFFFFull);

  // fp64 partial dot: lane covers elems [u*32, u*32+32)
  const float* zrow = z + (size_t)r * DIM;
  const float* crow = cb + (size_t)jg * DIM;
  double acc = 0.0;
#pragma unroll
  for (int t = 0; t < 8; ++t) {
    const float4 zv4 = *reinterpret_cast<const float4*>(zrow + u * 32 + t * 4);
    const float4 cv4 = *reinterpret_cast<const float4*>(crow + u * 32 + t * 4);
    acc += (double)zv4.x * cv4.x + (double)zv4.y * cv4.y +
           (double)zv4.z * cv4.z + (double)zv4.w * cv4.w;
  }
#pragma unroll
  for (int off = 1; off < 8; off <<= 1) acc += __shfl_xor(acc, off);
  // group leaders hold exact scores; cross-group argmin with lowest-j ties
  double s = (u == 0) ? (c2d[jg] - 2.0 * acc) : 1e300;
  uint32_t jj = (u == 0) ? jg : 0xFFFFFFFFu;
#pragma unroll
  for (int off = 8; off < 64; off <<= 1) {
    const double s2 = __shfl_xor(s, off);
    const uint32_t j2 = __shfl_xor(jj, off);
    if (s2 < s || (s2 == s && j2 < jj)) { s = s2; jj = j2; }
  }
  const uint32_t bestJ = __shfl(jj, 0);

  // gather z_q, write out, fp64 loss partial
  const float4 zv = *reinterpret_cast<const float4*>(zrow + lane * 4);
  const float4 q = *reinterpret_cast<const float4*>(
      cb + (size_t)bestJ * DIM + lane * 4);
  *reinterpret_cast<float4*>(out + (size_t)r * DIM + lane * 4) = q;
  const float dx = zv.x - q.x, dy = zv.y - q.y, dz = zv.z - q.z, dw = zv.w - q.w;
  double v = (double)dx * dx + (double)dy * dy + (double)dz * dz + (double)dw * dw;
#pragma unroll
  for (int off = 32; off > 0; off >>= 1) v += __shfl_xor(v, off);
  if (lane == 0) atomicAdd(&lossSlots[r & 255], v);
}

// ---- kernel 4: finalize loss (separate launch; kernel boundary = sync) ----
__global__ __launch_bounds__(256) void k_fin(const double* __restrict__ slots,
                                             float* __restrict__ out) {
  const int w = threadIdx.x >> 6, lane = threadIdx.x & 63;
  double v = slots[threadIdx.x];
#pragma unroll
  for (int off = 32; off > 0; off >>= 1) v += __shfl_xor(v, off);
  __shared__ double part[4];
  if (lane == 0) part[w] = v;
  __syncthreads();
  if (threadIdx.x == 0) {
    const double mse =
        (part[0] + part[1] + part[2] + part[3]) / (double)((size_t)NROWS * DIM);
    out[(size_t)NROWS * DIM] = (float)(1.1 * mse);   // 0.1*mse + mse
  }
}

extern "C" void kernel_launch(void* const* d_in, const int* in_sizes, int n_in,
                              void* d_out, int out_size, void* d_ws, size_t ws_size,
                              hipStream_t stream) {
  const float* z  = (const float*)d_in[0];
  const float* cb = (const float*)d_in[1];
  float* out = (float*)d_out;
  char* ws = (char*)d_ws;
  double* c2d = (double*)(ws + OFF_C2D);
  unsigned long long* ptop = (unsigned long long*)(ws + OFF_PTOP);
  double* lossSlots = (double*)(ws + OFF_LSLOT);
  unsigned short* z16  = (unsigned short*)(ws + OFF_Z16);
  unsigned short* cb16 = (unsigned short*)(ws + OFF_CB16);

  hipLaunchKernelGGL(k_prep, dim3(4096 + 2048 + 1), dim3(256), 0, stream,
                     z, cb, z16, cb16, c2d, lossSlots);
  hipLaunchKernelGGL(k_score, dim3((NROWS / BROWS) * (NCODES / PCOLS)),
                     dim3(256), 0, stream, z16, cb16, ptop);
  hipLaunchKernelGGL(k_refine_out, dim3(NROWS / 4), dim3(256), 0, stream,
                     z, cb, c2d, ptop, out, lossSlots);
  hipLaunchKernelGGL(k_fin, dim3(1), dim3(256), 0, stream, lossSlots, out);
}

// Round 9
// 212.559 us; speedup vs baseline: 1.0492x; 1.0492x over previous
//
#include <hip/hip_runtime.h>
#include <stdint.h>

#define NROWS 16384
#define NCODES 8192
#define DIM 256

#define BROWS 64
#define PCOLS 2048
#define BCOLS 128
#define NCITER (PCOLS / BCOLS)   // 16 citers x 4 K-chunks = 64 chunks

// workspace layout (bytes)
#define OFF_C2D   0u          // double[8192]             65536
#define OFF_PTOP  65536u      // u64[16384][4][2]       1048576
#define OFF_LSLOT 1114112u    // double[256]               2048
#define OFF_CB16  1116160u    // u16[8192*256]          4194304

typedef __attribute__((ext_vector_type(8))) short bf16x8;
typedef __attribute__((ext_vector_type(4))) float f32x4;

__device__ __forceinline__ uint32_t enc_f32(float f) {
  uint32_t u = __float_as_uint(f);
  return (u & 0x80000000u) ? ~u : (u | 0x80000000u);
}
__device__ __forceinline__ unsigned short f2bf(float f) {
  uint32_t u = __float_as_uint(f);
  u += 0x7fffu + ((u >> 16) & 1u);   // RNE (inputs finite)
  return (unsigned short)(u >> 16);
}
__device__ __forceinline__ void gload16(const void* g, void* l) {
  __builtin_amdgcn_global_load_lds(
      (const __attribute__((address_space(1))) unsigned int*)g,
      (__attribute__((address_space(3))) unsigned int*)l, 16, 0, 0);
}
__device__ __forceinline__ unsigned long long umin64(unsigned long long a,
                                                     unsigned long long b) {
  return a < b ? a : b;
}

// ---- kernel 1: prep — cb cvt + fp64 norms | loss-slot init ----
// (z16 pass removed round-9: k_score converts A in-kernel via cvt_pk)
__global__ __launch_bounds__(256) void k_prep(
    const float* __restrict__ cb, unsigned short* __restrict__ cb16,
    double* __restrict__ c2d, double* __restrict__ lossSlots) {
  const int bid = blockIdx.x;
  if (bid < 2048) {
    const int w = threadIdx.x >> 6, lane = threadIdx.x & 63;
    const int j = bid * 4 + w;
    float4 v = *reinterpret_cast<const float4*>(cb + (size_t)j * DIM + lane * 4);
    ushort4 o = {f2bf(v.x), f2bf(v.y), f2bf(v.z), f2bf(v.w)};
    *reinterpret_cast<ushort4*>(cb16 + (size_t)j * DIM + lane * 4) = o;
    double s = (double)v.x * v.x + (double)v.y * v.y +
               (double)v.z * v.z + (double)v.w * v.w;
#pragma unroll
    for (int off = 32; off > 0; off >>= 1) s += __shfl_xor(s, off);
    if (lane == 0) c2d[j] = s;
  } else {
    lossSlots[threadIdx.x] = 0.0;
  }
}

// ---- kernel 2: panel-persistent MFMA dot-max ----
// 1024 blocks: 4 col-panels x 256 row-panels, XCD-swizzled. Per block:
// 64 rows x 2048 cols, 16 citers of 128 cols x 4 K-chunks (16 MFMA/chunk).
// Round-9 structure: 2 x 16 KB B-buffers (34.8 KB LDS) -> 4 blocks/CU,
// grid = exactly 4/CU, zero tail. ONE barrier per chunk:
//   {vmcnt(0); s_barrier; STAGE(c+1); COMPUTE(c)}
// vmcnt(0) sits a full chunk of compute after the stage issue -> near-free
// (m97-class). Round-8 lesson: chunk granularity must stay >=16 MFMAs —
// smaller chunks lose latency hiding regardless of occupancy.
// launch_bounds (256,2): round-4 lesson — never cap regs below working set.
__global__ __launch_bounds__(256, 2) void k_score(
    const float* __restrict__ z, const unsigned short* __restrict__ cb16,
    unsigned long long* __restrict__ ptop) {
  __shared__ unsigned short pool[2 * BCOLS * 64];   // 2 x 16 KB
  __shared__ unsigned long long top_sh[BROWS][2][2];

  const int tid = threadIdx.x;
  const int lane = tid & 63;
  const int w = tid >> 6;
  const int wr = w >> 1, wc = w & 1;
  const int l15 = lane & 15, l4 = lane >> 4;

  // bijective XCD swizzle (1024 % 8 == 0), col-panel-major
  const int wg = (blockIdx.x & 7) * 128 + (blockIdx.x >> 3);
  const int panel = wg >> 8;          // 0..3
  const int row0 = (wg & 255) * BROWS;
  const int col0 = panel * PCOLS;

  // ---- A: f32 global -> cvt_pk -> bf16 registers (rows wr*32.., whole K) ----
  bf16x8 a_reg[2][8];
#pragma unroll
  for (int mi = 0; mi < 2; ++mi)
#pragma unroll
    for (int kt = 0; kt < 8; ++kt) {
      const float* p = z + (size_t)(row0 + wr * 32 + mi * 16 + l15) * DIM +
                       kt * 32 + l4 * 8;
      const float4 u0 = *reinterpret_cast<const float4*>(p);
      const float4 u1 = *reinterpret_cast<const float4*>(p + 4);
      union { bf16x8 v; uint32_t u[4]; } af;
      asm("v_cvt_pk_bf16_f32 %0, %1, %2" : "=v"(af.u[0]) : "v"(u0.x), "v"(u0.y));
      asm("v_cvt_pk_bf16_f32 %0, %1, %2" : "=v"(af.u[1]) : "v"(u0.z), "v"(u0.w));
      asm("v_cvt_pk_bf16_f32 %0, %1, %2" : "=v"(af.u[2]) : "v"(u1.x), "v"(u1.y));
      asm("v_cvt_pk_bf16_f32 %0, %1, %2" : "=v"(af.u[3]) : "v"(u1.z), "v"(u1.w));
      a_reg[mi][kt] = af.v;
    }
  asm volatile("s_waitcnt vmcnt(0)" ::: "memory");
  __builtin_amdgcn_sched_barrier(0);

  // B staging constants (pre-swizzled global source; LDS stays linear).
  const int bc_loc = tid >> 3;                                         // 0..31
  const int kswz_e = ((((tid & 7) * 16) ^ (((tid >> 3) & 7) << 4)) >> 1);
  const unsigned wbase = (unsigned)w * 1024u;

#define STAGE(ci_, kc_, buf_) do {                                             \
    const unsigned short* gsrc_ = cb16 +                                       \
        (size_t)(col0 + (ci_) * BCOLS + bc_loc) * DIM + (kc_) * 64 + kswz_e;   \
    char* ldst_ = (char*)pool + (buf_) * 16384 + wbase;                        \
    gload16(gsrc_,            ldst_);                                          \
    gload16(gsrc_ + 32 * DIM, ldst_ + 4096);                                   \
    gload16(gsrc_ + 64 * DIM, ldst_ + 8192);                                   \
    gload16(gsrc_ + 96 * DIM, ldst_ + 12288);                                  \
  } while (0)

#define COMPUTE(kc_, buf_) do {                                                \
    _Pragma("unroll")                                                          \
    for (int kk_ = 0; kk_ < 2; ++kk_) {                                        \
      bf16x8 bf_[4];                                                           \
      _Pragma("unroll")                                                        \
      for (int ni_ = 0; ni_ < 4; ++ni_) {                                      \
        const int cI_ = wc * 64 + ni_ * 16 + l15;                              \
        const int kb_ = (kk_ * 64 + l4 * 16) ^ ((l15 & 7) << 4);               \
        bf_[ni_] = *reinterpret_cast<const bf16x8*>(                           \
            (const char*)pool + (buf_) * 16384 + cI_ * 128 + kb_);             \
      }                                                                        \
      _Pragma("unroll")                                                        \
      for (int mi_ = 0; mi_ < 2; ++mi_)                                        \
        _Pragma("unroll")                                                      \
        for (int ni_ = 0; ni_ < 4; ++ni_)                                      \
          acc[mi_][ni_] = __builtin_amdgcn_mfma_f32_16x16x32_bf16(             \
              a_reg[mi_][(kc_) * 2 + kk_], bf_[ni_], acc[mi_][ni_], 0, 0, 0);  \
    }                                                                          \
  } while (0)

// one barrier per chunk; vmcnt(0) is a full chunk after the stage issue
#define CHN(kc_, bufR_, sci_, skc_, bufS_)                                     \
  asm volatile("s_waitcnt vmcnt(0)" ::: "memory");                             \
  __builtin_amdgcn_sched_barrier(0);                                           \
  __builtin_amdgcn_s_barrier();                                                \
  __builtin_amdgcn_sched_barrier(0);                                           \
  STAGE(sci_, skc_, bufS_);                                                    \
  __builtin_amdgcn_s_setprio(1);                                               \
  COMPUTE(kc_, bufR_);                                                         \
  __builtin_amdgcn_s_setprio(0);

#define CHT(kc_, bufR_)                                                        \
  asm volatile("s_waitcnt vmcnt(0)" ::: "memory");                             \
  __builtin_amdgcn_sched_barrier(0);                                           \
  __builtin_amdgcn_s_barrier();                                                \
  __builtin_amdgcn_sched_barrier(0);                                           \
  __builtin_amdgcn_s_setprio(1);                                               \
  COMPUTE(kc_, bufR_);                                                         \
  __builtin_amdgcn_s_setprio(0);

#define ZERO_ACC() do {                                                        \
    _Pragma("unroll")                                                          \
    for (int mi_ = 0; mi_ < 2; ++mi_)                                          \
      _Pragma("unroll")                                                        \
      for (int ni_ = 0; ni_ < 4; ++ni_)                                        \
        acc[mi_][ni_] = (f32x4){0.f, 0.f, 0.f, 0.f};                           \
  } while (0)

#define EPI(ci_) do {                                                          \
    const uint32_t cbase = (uint32_t)(col0 + (ci_) * BCOLS + wc * 64 + l15);   \
    _Pragma("unroll")                                                          \
    for (int mi_ = 0; mi_ < 2; ++mi_)                                          \
      _Pragma("unroll")                                                        \
      for (int q_ = 0; q_ < 4; ++q_) {                                         \
        const int s_ = mi_ * 4 + q_;                                           \
        const float d0 = acc[mi_][0][q_], d1 = acc[mi_][1][q_];                \
        const float d2 = acc[mi_][2][q_], d3 = acc[mi_][3][q_];                \
        const float m01 = fmaxf(d0, d1);                                       \
        const uint32_t c01 = d1 > d0 ? cbase + 16u : cbase;                    \
        const float m23 = fmaxf(d2, d3);                                       \
        const uint32_t c23 = d3 > d2 ? cbase + 48u : cbase + 32u;              \
        const float mv = fmaxf(m01, m23);                                      \
        const uint32_t mc = m23 > m01 ? c23 : c01;                             \
        const bool g0 = mv > b0v[s_];                                          \
        const bool g1 = mv > b1v[s_];                                          \
        b1v[s_] = g0 ? b0v[s_] : (g1 ? mv : b1v[s_]);                          \
        b1c[s_] = g0 ? b0c[s_] : (g1 ? mc : b1c[s_]);                          \
        b0v[s_] = g0 ? mv : b0v[s_];                                           \
        b0c[s_] = g0 ? mc : b0c[s_];                                           \
      }                                                                        \
  } while (0)

// chunk c = 4*ci+kc, buf = kc&1 (BCOLS chunks per citer = 4, even); stage c+1.
#define CITER_F(ci_) ZERO_ACC();                                               \
  CHN(0, 0, ci_, 1, 1) CHN(1, 1, ci_, 2, 0)                                    \
  CHN(2, 0, ci_, 3, 1) CHN(3, 1, (ci_) + 1, 0, 0) EPI(ci_);

  f32x4 acc[2][4];
  float b0v[8], b1v[8];
  uint32_t b0c[8], b1c[8];
#pragma unroll
  for (int s = 0; s < 8; ++s) {
    b0v[s] = -1e30f; b1v[s] = -1e30f; b0c[s] = 0u; b1c[s] = 0u;
  }

  // prologue: stage chunk 0
  STAGE(0, 0, 0);

  // main: citers 0..14, then tail citer 15 (chunk 63 has no stage)
  for (int ci = 0; ci < 15; ++ci) {
    CITER_F(ci)
  }
  ZERO_ACC();
  CHN(0, 0, 15, 1, 1) CHN(1, 1, 15, 2, 0) CHN(2, 0, 15, 3, 1)
  CHT(3, 1) EPI(15);

  // ---- block end: top-2 butterfly over l15 lanes, wc-merge, plain store ----
#pragma unroll
  for (int mi = 0; mi < 2; ++mi)
#pragma unroll
    for (int q = 0; q < 4; ++q) {
      const int s = mi * 4 + q;
      unsigned long long p0 =
          ((unsigned long long)enc_f32(-2.0f * b0v[s]) << 32) | b0c[s];
      unsigned long long p1 =
          ((unsigned long long)enc_f32(-2.0f * b1v[s]) << 32) | b1c[s];
#pragma unroll
      for (int off = 1; off < 16; off <<= 1) {
        const unsigned long long o0 = __shfl_xor(p0, off);
        const unsigned long long o1 = __shfl_xor(p1, off);
        const unsigned long long hi = p0 > o0 ? p0 : o0;
        p0 = umin64(p0, o0);
        p1 = umin64(hi, umin64(p1, o1));
      }
      if (l15 == 0) {
        const int rloc = wr * 32 + mi * 16 + l4 * 4 + q;
        top_sh[rloc][wc][0] = p0;
        top_sh[rloc][wc][1] = p1;
      }
    }
  __syncthreads();
  if (tid < BROWS) {
    const unsigned long long a0 = top_sh[tid][0][0], a1 = top_sh[tid][0][1];
    const unsigned long long c0 = top_sh[tid][1][0], c1 = top_sh[tid][1][1];
    const unsigned long long hi = a0 > c0 ? a0 : c0;
    ptop[(size_t)(row0 + tid) * 8 + panel * 2 + 0] = umin64(a0, c0);
    ptop[(size_t)(row0 + tid) * 8 + panel * 2 + 1] = umin64(hi, umin64(a1, c1));
  }
#undef STAGE
#undef COMPUTE
#undef CHN
#undef CHT
#undef ZERO_ACC
#undef EPI
#undef CITER_F
}

// ---- kernel 3: parallel fp64 refine (8 fixed candidates) + gather + loss ----
// wave per row; 8 lane-groups of 8 each score one candidate concurrently.
// NO cross-block signaling / fences (round-6 lesson).
__global__ __launch_bounds__(256) void k_refine_out(
    const float* __restrict__ z, const float* __restrict__ cb,
    const double* __restrict__ c2d, const unsigned long long* __restrict__ ptop,
    float* __restrict__ out, double* __restrict__ lossSlots) {
  const int w = threadIdx.x >> 6;
  const int lane = threadIdx.x & 63;
  const int r = blockIdx.x * 4 + w;
  const int g = lane >> 3;     // candidate slot 0..7 ([panel][2])
  const int u = lane & 7;

  const uint32_t jg =
      (uint32_t)(ptop[(size_t)r * 8 + g] & 0xFFFFFFFFull);

  // fp64 partial dot: lane covers elems [u*32, u*32+32)
  const float* zrow = z + (size_t)r * DIM;
  const float* crow = cb + (size_t)jg * DIM;
  double acc = 0.0;
#pragma unroll
  for (int t = 0; t < 8; ++t) {
    const float4 zv4 = *reinterpret_cast<const float4*>(zrow + u * 32 + t * 4);
    const float4 cv4 = *reinterpret_cast<const float4*>(crow + u * 32 + t * 4);
    acc += (double)zv4.x * cv4.x + (double)zv4.y * cv4.y +
           (double)zv4.z * cv4.z + (double)zv4.w * cv4.w;
  }
#pragma unroll
  for (int off = 1; off < 8; off <<= 1) acc += __shfl_xor(acc, off);
  // group leaders hold exact scores; cross-group argmin with lowest-j ties
  double s = (u == 0) ? (c2d[jg] - 2.0 * acc) : 1e300;
  uint32_t jj = (u == 0) ? jg : 0xFFFFFFFFu;
#pragma unroll
  for (int off = 8; off < 64; off <<= 1) {
    const double s2 = __shfl_xor(s, off);
    const uint32_t j2 = __shfl_xor(jj, off);
    if (s2 < s || (s2 == s && j2 < jj)) { s = s2; jj = j2; }
  }
  const uint32_t bestJ = __shfl(jj, 0);

  // gather z_q, write out, fp64 loss partial
  const float4 zv = *reinterpret_cast<const float4*>(zrow + lane * 4);
  const float4 q = *reinterpret_cast<const float4*>(
      cb + (size_t)bestJ * DIM + lane * 4);
  *reinterpret_cast<float4*>(out + (size_t)r * DIM + lane * 4) = q;
  const float dx = zv.x - q.x, dy = zv.y - q.y, dz = zv.z - q.z, dw = zv.w - q.w;
  double v = (double)dx * dx + (double)dy * dy + (double)dz * dz + (double)dw * dw;
#pragma unroll
  for (int off = 32; off > 0; off >>= 1) v += __shfl_xor(v, off);
  if (lane == 0) atomicAdd(&lossSlots[r & 255], v);
}

// ---- kernel 4: finalize loss (separate launch; kernel boundary = sync) ----
__global__ __launch_bounds__(256) void k_fin(const double* __restrict__ slots,
                                             float* __restrict__ out) {
  const int w = threadIdx.x >> 6, lane = threadIdx.x & 63;
  double v = slots[threadIdx.x];
#pragma unroll
  for (int off = 32; off > 0; off >>= 1) v += __shfl_xor(v, off);
  __shared__ double part[4];
  if (lane == 0) part[w] = v;
  __syncthreads();
  if (threadIdx.x == 0) {
    const double mse =
        (part[0] + part[1] + part[2] + part[3]) / (double)((size_t)NROWS * DIM);
    out[(size_t)NROWS * DIM] = (float)(1.1 * mse);   // 0.1*mse + mse
  }
}

extern "C" void kernel_launch(void* const* d_in, const int* in_sizes, int n_in,
                              void* d_out, int out_size, void* d_ws, size_t ws_size,
                              hipStream_t stream) {
  const float* z  = (const float*)d_in[0];
  const float* cb = (const float*)d_in[1];
  float* out = (float*)d_out;
  char* ws = (char*)d_ws;
  double* c2d = (double*)(ws + OFF_C2D);
  unsigned long long* ptop = (unsigned long long*)(ws + OFF_PTOP);
  double* lossSlots = (double*)(ws + OFF_LSLOT);
  unsigned short* cb16 = (unsigned short*)(ws + OFF_CB16);

  hipLaunchKernelGGL(k_prep, dim3(2048 + 1), dim3(256), 0, stream,
                     cb, cb16, c2d, lossSlots);
  hipLaunchKernelGGL(k_score, dim3((NROWS / BROWS) * (NCODES / PCOLS)),
                     dim3(256), 0, stream, z, cb16, ptop);
  hipLaunchKernelGGL(k_refine_out, dim3(NROWS / 4), dim3(256), 0, stream,
                     z, cb, c2d, ptop, out, lossSlots);
  hipLaunchKernelGGL(k_fin, dim3(1), dim3(256), 0, stream, lossSlots, out);
}